// Round 11
// baseline (19.888 us; speedup 1.0000x reference)
//
#include <hip/hip_runtime.h>

// out[b, f*64+n] = sum_c sum_j x[b, c*64+j] * w[f, c, (n-j)&63]
// R11: phase-diversity attack. 512-thr blocks (8 waves), 2 blocks/CU
// (73728B LDS each, 147KB/CU), grid 512 = 64 f x 8 row-octants, q=bid&7
// -> one octant per XCD (A set 256KB L2-resident). setprio(1) around MFMA
// clusters (T5). Depth-2 named-set A-prefetch + sched_barrier kept from R10.

#define KDIM 4096

typedef __attribute__((ext_vector_type(8)))  short s16x8;
typedef __attribute__((ext_vector_type(4)))  float f32x4;
typedef __attribute__((ext_vector_type(16))) float f32x16;
typedef unsigned short u16;

__device__ __forceinline__ u16 f2bf(float f) {
  unsigned int u = __float_as_uint(f);
  u += 0x7FFF + ((u >> 16) & 1);   // round-to-nearest-even
  return (u16)(u >> 16);
}

// ---- pack x (fp32 256x4096) -> Xp bf16 in 32x32x16-A-fragment order ----
// (byte-identical to R7)
__global__ __launch_bounds__(256) void pack_kernel(const float* __restrict__ x,
                                                   u16* __restrict__ Xp) {
  __shared__ __align__(16) u16 tile[32 * 264];
  const int tid = threadIdx.x;
  const int rg  = blockIdx.x >> 4;
  const int cg  = blockIdx.x & 15;

  #pragma unroll
  for (int i = 0; i < 4; ++i) {
    int g    = i * 2048 + tid * 8;
    int row  = g >> 8;
    int kloc = g & 255;
    const float4* src = (const float4*)(x + (size_t)(rg * 32 + row) * 4096 + cg * 256 + kloc);
    float4 v0 = src[0], v1 = src[1];
    union { u16 u[8]; uint4 v; } o;
    o.u[0] = f2bf(v0.x); o.u[1] = f2bf(v0.y); o.u[2] = f2bf(v0.z); o.u[3] = f2bf(v0.w);
    o.u[4] = f2bf(v1.x); o.u[5] = f2bf(v1.y); o.u[6] = f2bf(v1.z); o.u[7] = f2bf(v1.w);
    *(uint4*)(tile + row * 264 + kloc) = o.v;
  }
  __syncthreads();

  const int lane = tid & 63;
  const int fw   = tid >> 6;
  #pragma unroll
  for (int i = 0; i < 4; ++i) {
    int fidx = i * 4 + fw;
    int cl   = fidx >> 2;
    int kk   = fidx & 3;
    int c    = cg * 4 + cl;
    uint4 v = *(const uint4*)(tile + (lane & 31) * 264 + cl * 64 + kk * 16 + (lane >> 5) * 8);
    size_t u = ((size_t)((c * 8 + rg) * 4 + kk) << 6) + lane;
    *(uint4*)(Xp + (u << 3)) = v;
  }
}

// ---- fused circulant GEMM: 8 waves, 2 blocks/CU, setprio MFMA ----
__global__ __launch_bounds__(512, 4) void gemm_two(const u16* __restrict__ Xp,
                                                   const float* __restrict__ w,
                                                   float* __restrict__ out) {
  extern __shared__ __align__(16) char pool[];   // 73728 B
  u16*   tab = (u16*)pool;                       // [c][576] u16
  float* red = (float*)pool;                     // epilogue: 8 slots x 8 KB

  const int tid   = threadIdx.x;
  const int lane  = tid & 63;
  const int wid   = tid >> 6;        // 0..7 = cslot
  const int l31   = lane & 31;
  const int lh    = lane >> 5;
  const int f     = blockIdx.x >> 3;
  const int q     = blockIdx.x & 7;  // 32-row octant; == XCD id

  // build all 64 circulant tables: wave wid builds c = wid*8 .. wid*8+7
  const float* wf = w + ((size_t)f << 12);
  #pragma unroll
  for (int j = 0; j < 8; ++j) {
    int c = wid * 8 + j;
    u16 bv = f2bf(wf[(c << 6) + lane]);
    u16* T = tab + c * 576;
    #pragma unroll
    for (int m = 0; m < 8; ++m) {
      int i = (-(lane + m)) & 63;
      T[m * 72 + i] = bv;
    }
  }

  int bofs0, bofs1, bofs2, bofs3;
  {
    int i0;
    i0 = (lh * 8 - l31)      & 63; bofs0 = (i0 & 7) * 71 + i0;
    i0 = (lh * 8 - l31 - 16) & 63; bofs1 = (i0 & 7) * 71 + i0;
    i0 = (lh * 8 - l31 - 32) & 63; bofs2 = (i0 & 7) * 71 + i0;
    i0 = (lh * 8 - l31 - 48) & 63; bofs3 = (i0 & 7) * 71 + i0;
  }

  // A-frag base: 16B unit = ((c*8+rg)*4+kk)*64+lane, rg = q; c = 8t+wid
  const u16* abase = Xp + ((size_t)(wid * 8 + q) * 2048 + lane * 8);

  // 3 named A register sets (depth-2 prefetch, un-collapsible)
  s16x8 A0_0, A0_1, A0_2, A0_3;
  s16x8 A1_0, A1_1, A1_2, A1_3;
  s16x8 A2_0, A2_1, A2_2, A2_3;

  #define ALOAD(SET, T)                                       \
    { const u16* nb_ = abase + (size_t)(T) * 131072;          \
      A##SET##_0 = *(const s16x8*)(nb_);                      \
      A##SET##_1 = *(const s16x8*)(nb_ + 512);                \
      A##SET##_2 = *(const s16x8*)(nb_ + 1024);               \
      A##SET##_3 = *(const s16x8*)(nb_ + 1536); }

  ALOAD(0, 0)
  ALOAD(1, 1)

  f32x16 acc0 = {}, acc1 = {};

  __syncthreads();                   // tables visible

  #define STEP(T, CUR, PRE, DOPRE)                                            \
    {                                                                         \
      if (DOPRE) ALOAD(PRE, (T) + 2)                                          \
      const u16* Tb = tab + (8 * (T) + wid) * 576;                            \
      s16x8 b0 = *(const s16x8*)(Tb + bofs0);                                 \
      s16x8 b1 = *(const s16x8*)(Tb + bofs1);                                 \
      s16x8 b2 = *(const s16x8*)(Tb + bofs2);                                 \
      s16x8 b3 = *(const s16x8*)(Tb + bofs3);                                 \
      __builtin_amdgcn_sched_barrier(0);                                      \
      __builtin_amdgcn_s_setprio(1);                                          \
      acc0 = __builtin_amdgcn_mfma_f32_32x32x16_bf16(A##CUR##_0, b0, acc0, 0, 0, 0); \
      acc1 = __builtin_amdgcn_mfma_f32_32x32x16_bf16(A##CUR##_0, b2, acc1, 0, 0, 0); \
      acc0 = __builtin_amdgcn_mfma_f32_32x32x16_bf16(A##CUR##_1, b3, acc0, 0, 0, 0); \
      acc1 = __builtin_amdgcn_mfma_f32_32x32x16_bf16(A##CUR##_1, b1, acc1, 0, 0, 0); \
      acc0 = __builtin_amdgcn_mfma_f32_32x32x16_bf16(A##CUR##_2, b2, acc0, 0, 0, 0); \
      acc1 = __builtin_amdgcn_mfma_f32_32x32x16_bf16(A##CUR##_2, b0, acc1, 0, 0, 0); \
      acc0 = __builtin_amdgcn_mfma_f32_32x32x16_bf16(A##CUR##_3, b1, acc0, 0, 0, 0); \
      acc1 = __builtin_amdgcn_mfma_f32_32x32x16_bf16(A##CUR##_3, b3, acc1, 0, 0, 0); \
      __builtin_amdgcn_s_setprio(0);                                          \
    }

  STEP(0, 0, 2, 1)
  STEP(1, 1, 0, 1)
  STEP(2, 2, 1, 1)
  STEP(3, 0, 2, 1)
  STEP(4, 1, 0, 1)
  STEP(5, 2, 1, 1)
  STEP(6, 0, 2, 0)
  STEP(7, 1, 2, 0)

  // ---- flattened epilogue: 2 barriers ----
  __syncthreads();                   // all table reads done; reuse pool
  {
    float* slot = red + wid * 2048;  // 8 KB per wave
    #pragma unroll
    for (int i = 0; i < 4; ++i) {
      f32x4 v0 = {acc0[4*i], acc0[4*i+1], acc0[4*i+2], acc0[4*i+3]};
      f32x4 v1 = {acc1[4*i], acc1[4*i+1], acc1[4*i+2], acc1[4*i+3]};
      *(f32x4*)(slot + ((i)     * 64 + lane) * 4) = v0;
      *(f32x4*)(slot + ((i + 4) * 64 + lane) * 4) = v1;
    }
  }
  __syncthreads();
  {
    const int ii = tid >> 6;             // 0..3 acc0 quads, 4..7 acc1 quads
    const int sl = tid & 63;             // source lane
    f32x4 s = {};
    #pragma unroll
    for (int cs = 0; cs < 8; ++cs)
      s += *(const f32x4*)(red + (size_t)cs * 2048 + (ii * 64 + sl) * 4);
    // C/D layout (m74/m101): col = lane&31, row = (reg&3)+8*(reg>>2)+4*(lane>>5)
    const int col  = (f << 6) + (ii >> 2) * 32 + (sl & 31);
    const int rowb = q * 32 + 8 * (ii & 3) + 4 * (sl >> 5);
    #pragma unroll
    for (int e = 0; e < 4; ++e)
      out[(size_t)(rowb + e) * 4096 + col] = s[e];
  }
}

extern "C" void kernel_launch(void* const* d_in, const int* in_sizes, int n_in,
                              void* d_out, int out_size, void* d_ws, size_t ws_size,
                              hipStream_t stream) {
  const float* x = (const float*)d_in[0];    // (256, 4096) fp32
  const float* w = (const float*)d_in[1];    // (64, 64, 64) fp32
  float* out = (float*)d_out;                // (256, 4096) fp32

  u16* Xp = (u16*)d_ws;                      // 2 MB packed bf16 X

  pack_kernel<<<128, 256, 0, stream>>>(x, Xp);
  gemm_two<<<512, 512, 73728, stream>>>(Xp, w, out);
}